// Round 5
// baseline (297.394 us; speedup 1.0000x reference)
//
#include <hip/hip_runtime.h>
#include <float.h>

// VQ-VAE vector quantizer, MI355X fp32 vector-ALU version, round 5.
// z: [32,64,32,32] f32, codebook: [1024,64] f32
// out (f32 flat): z_q [2097152] | loss [1] | indices-as-float [32768]
//
// Numerics contract (DO NOT CHANGE — bitwise-matches the numpy fp32 ref):
//  - code/pixel norms: numpy pairwise-sum tree over 64 rounded squares,
//    fp contract OFF
//  - dot: single c-ordered fma chain per (pixel, code)  (== BLAS sgemm
//    microkernel accumulation)
//  - score: fl(fl(zz+ee) - 2*dot); strict-< first-min, codes visited in
//    ascending-k order at every reduction level (k-step, wave, slice)
//
// Round-5 perf change: rounds 2-4 never kept the 64-float pixel vector in
// VGPRs (VGPR_Count 40-76 proves it) — the k-loop was re-fetching z every
// iteration, so only ~half of VALU issue was FMA. Now z lives in LDS as
// [c/4][px] float4 (one ds_read_b128 per 4-channel chunk, immediate-offset
// addressing, zero addr VALU) and codebook rows stream through SGPRs
// (s_load; SGPR operand folded into v_fmac). Hot-loop register need ~25.

#define DIM       64
#define N_EMB     1024
#define N_PX      32768
#define LOSS_OFF  2097152
#define IDX_OFF   2097153
// loss = 1.25 * sum / 2^21  (exact fp32 constant)
#define LOSS_SCALE 5.9604644775390625e-07f

// numpy pairwise_sum of squares over a 64-float global row, exact tree.
__device__ __forceinline__ float np_sumsq64_row(const float* __restrict__ row) {
    #pragma clang fp contract(off)
    float r[8];
    #pragma unroll
    for (int j = 0; j < 8; ++j) {
        float s = row[j] * row[j];
        #pragma unroll
        for (int m = 1; m < 8; ++m) {
            float p = row[j + 8 * m] * row[j + 8 * m];
            s = s + p;
        }
        r[j] = s;
    }
    return ((r[0] + r[1]) + (r[2] + r[3])) + ((r[4] + r[5]) + (r[6] + r[7]));
}

// Phase 1: grid 2048 = 512 px-groups x 4 code-slices; 256 thr (4 waves).
// Lane owns 1 pixel; wave w owns codes [slice*256 + w*64, +64).
__global__ __launch_bounds__(256, 8)
void vq_argmin(const float* __restrict__ z, const float* __restrict__ cb,
               float* __restrict__ ws_val, int* __restrict__ ws_idx,
               float* __restrict__ out) {
    __shared__ float4 ldsZ[16 * 64];   // [c4][px], 16 KB
    __shared__ float  esq[256];        // this slice's code norms
    __shared__ float  cand_val[4 * 64];
    __shared__ int    cand_idx[4 * 64];

    const int tid  = threadIdx.x;
    const int lane = tid & 63;
    const int wave = __builtin_amdgcn_readfirstlane(tid >> 6);  // uniform
    const int g    = blockIdx.x >> 2;      // px-group 0..511 (64 px each)
    const int s    = blockIdx.x & 3;       // code slice 0..3 (256 codes)
    const int n0   = g * 64;
    const int b    = n0 >> 10;
    const int hw0  = n0 & 1023;
    const size_t zbase = (size_t)b * 65536 + (size_t)hw0;   // z[b][c][hw]

    // ---- stage z tile -> LDS [c4][px] (transposing gather, coalesced) ----
    {
        const int px = tid & 63;
        const int cq = tid >> 6;           // 0..3
        #pragma unroll
        for (int r = 0; r < 4; ++r) {
            const int c4 = cq * 4 + r;
            const float* zp = z + zbase + (size_t)(c4 * 4) * 1024 + px;
            float4 v;
            v.x = zp[0];
            v.y = zp[1024];
            v.z = zp[2048];
            v.w = zp[3072];
            ldsZ[c4 * 64 + px] = v;
        }
    }

    // ---- slice code norms -> LDS (1 row per thread), numpy tree ----
    esq[tid] = np_sumsq64_row(cb + (size_t)(s * 256 + tid) * DIM);

    __syncthreads();

    // ---- zz for this lane's pixel, numpy tree from LDS (bit-identical) ----
    float zz;
    {
        #pragma clang fp contract(off)
        float4 qa = ldsZ[lane];            // c = 0..3
        float4 qb = ldsZ[64 + lane];       // c = 4..7
        float r0 = qa.x * qa.x, r1 = qa.y * qa.y, r2 = qa.z * qa.z, r3 = qa.w * qa.w;
        float r4 = qb.x * qb.x, r5 = qb.y * qb.y, r6 = qb.z * qb.z, r7 = qb.w * qb.w;
        #pragma unroll
        for (int m = 1; m < 8; ++m) {      // r[j] += sq[j + 8m], m ascending
            qa = ldsZ[(2 * m) * 64 + lane];
            qb = ldsZ[(2 * m + 1) * 64 + lane];
            float p;
            p = qa.x * qa.x; r0 = r0 + p;
            p = qa.y * qa.y; r1 = r1 + p;
            p = qa.z * qa.z; r2 = r2 + p;
            p = qa.w * qa.w; r3 = r3 + p;
            p = qb.x * qb.x; r4 = r4 + p;
            p = qb.y * qb.y; r5 = r5 + p;
            p = qb.z * qb.z; r6 = r6 + p;
            p = qb.w * qb.w; r7 = r7 + p;
        }
        zz = ((r0 + r1) + (r2 + r3)) + ((r4 + r5) + (r6 + r7));
    }

    // ---- argmin over this wave's 64-code slice, 8 codes per k-step ----
    float best = FLT_MAX;
    int   bidx = 0;
    const int kb = s * 256 + wave * 64;    // global code base (uniform)
    const int lb = wave * 64;              // local esq base
    for (int kk = 0; kk < 64; kk += 8) {
        const float* e = cb + (size_t)(kb + kk) * DIM;  // uniform -> s_load
        float d0 = 0.f, d1 = 0.f, d2 = 0.f, d3 = 0.f;
        float d4 = 0.f, d5 = 0.f, d6 = 0.f, d7 = 0.f;
        #pragma unroll
        for (int c4 = 0; c4 < 16; ++c4) {
            const float4 vzc = ldsZ[c4 * 64 + lane];   // imm-offset b128
            const int c0 = c4 * 4;
#define VQ_FMA4(DJ, J) \
            DJ = __builtin_fmaf(e[(J)*DIM + c0    ], vzc.x, DJ); \
            DJ = __builtin_fmaf(e[(J)*DIM + c0 + 1], vzc.y, DJ); \
            DJ = __builtin_fmaf(e[(J)*DIM + c0 + 2], vzc.z, DJ); \
            DJ = __builtin_fmaf(e[(J)*DIM + c0 + 3], vzc.w, DJ);
            VQ_FMA4(d0, 0) VQ_FMA4(d1, 1) VQ_FMA4(d2, 2) VQ_FMA4(d3, 3)
            VQ_FMA4(d4, 4) VQ_FMA4(d5, 5) VQ_FMA4(d6, 6) VQ_FMA4(d7, 7)
#undef VQ_FMA4
        }
        // scores, ascending j => first-min kept
#define VQ_SCORE(DJ, J) \
        { \
            float sc; \
            { \
                _Pragma("clang fp contract(off)") \
                const float p = zz + esq[lb + kk + (J)]; \
                sc = p - 2.0f * DJ; \
            } \
            if (sc < best) { best = sc; bidx = kb + kk + (J); } \
        }
        VQ_SCORE(d0, 0) VQ_SCORE(d1, 1) VQ_SCORE(d2, 2) VQ_SCORE(d3, 3)
        VQ_SCORE(d4, 4) VQ_SCORE(d5, 5) VQ_SCORE(d6, 6) VQ_SCORE(d7, 7)
#undef VQ_SCORE
    }
    cand_val[wave * 64 + lane] = best;
    cand_idx[wave * 64 + lane] = bidx;
    __syncthreads();

    // ---- block reduce (4 waves, ascending w == ascending k) -> ws ----
    if (tid < 64) {
        float bv = cand_val[tid];
        int   bi = cand_idx[tid];
        #pragma unroll
        for (int w = 1; w < 4; ++w) {
            float v = cand_val[w * 64 + tid];
            int   i = cand_idx[w * 64 + tid];
            if (v < bv || (v == bv && i < bi)) { bv = v; bi = i; }
        }
        ws_val[s * N_PX + n0 + tid] = bv;
        ws_idx[s * N_PX + n0 + tid] = bi;
    }
    // zero the loss accumulator for phase 2 (stream-ordered before vq_out)
    if (blockIdx.x == 0 && tid == 0) out[LOSS_OFF] = 0.f;
}

// Phase 2: grid 512 x 256 thr; block = 64 px. Reduce 4 slice-candidates
// (ascending slice == ascending k), write indices, z_q, loss.
__global__ __launch_bounds__(256, 4)
void vq_out(const float* __restrict__ z, const float* __restrict__ cb,
            const float* __restrict__ ws_val, const int* __restrict__ ws_idx,
            float* __restrict__ out) {
    __shared__ int   fidx[64];
    __shared__ float lred[4];

    const int tid  = threadIdx.x;
    const int lane = tid & 63;
    const int wave = tid >> 6;
    const int n0   = blockIdx.x * 64;
    const int b    = n0 >> 10;
    const int hw0  = n0 & 1023;
    const size_t zbase = (size_t)b * 65536 + (size_t)hw0;

    if (tid < 64) {
        float bv = ws_val[n0 + tid];
        int   bi = ws_idx[n0 + tid];
        #pragma unroll
        for (int sl = 1; sl < 4; ++sl) {
            float v = ws_val[sl * N_PX + n0 + tid];
            int   i = ws_idx[sl * N_PX + n0 + tid];
            if (v < bv || (v == bv && i < bi)) { bv = v; bi = i; }
        }
        fidx[tid] = bi;
        out[IDX_OFF + n0 + tid] = (float)bi;
    }
    __syncthreads();

    const int px = tid & 63;
    const int cg = tid >> 6;      // 0..3 -> channels cg*16 .. cg*16+15
    const int mi = fidx[px];
    float lacc = 0.f;
    #pragma unroll
    for (int i = 0; i < 16; ++i) {
        const int c = cg * 16 + i;
        float q  = cb[mi * DIM + c];                    // L2-resident gather
        size_t go = zbase + (size_t)c * 1024 + px;
        float zv = z[go];                               // coalesced
        float d  = q - zv;
        lacc = __builtin_fmaf(d, d, lacc);
        out[go] = q;                                    // coalesced
    }
    #pragma unroll
    for (int off = 32; off > 0; off >>= 1)
        lacc += __shfl_down(lacc, off, 64);
    if (lane == 0) lred[wave] = lacc;
    __syncthreads();
    if (tid == 0) {
        float t = (lred[0] + lred[1]) + (lred[2] + lred[3]);
        atomicAdd(&out[LOSS_OFF], t * LOSS_SCALE);
    }
}

extern "C" void kernel_launch(void* const* d_in, const int* in_sizes, int n_in,
                              void* d_out, int out_size, void* d_ws, size_t ws_size,
                              hipStream_t stream) {
    const float* z  = (const float*)d_in[0];   // 2097152 f32
    const float* cb = (const float*)d_in[1];   // 65536 f32
    float* out = (float*)d_out;
    // workspace: 4 x 32768 candidate vals (512 KB) + 4 x 32768 idx (512 KB)
    float* ws_val = (float*)d_ws;
    int*   ws_idx = (int*)((char*)d_ws + 4u * N_PX * sizeof(float));

    vq_argmin<<<2048, 256, 0, stream>>>(z, cb, ws_val, ws_idx, out);
    vq_out<<<512, 256, 0, stream>>>(z, cb, ws_val, ws_idx, out);
}

// Round 6
// 152.244 us; speedup vs baseline: 1.9534x; 1.9534x over previous
//
#include <hip/hip_runtime.h>
#include <float.h>

// VQ-VAE vector quantizer, MI355X fp32 vector-ALU version, round 6.
// z: [32,64,32,32] f32, codebook: [1024,64] f32
// out (f32 flat): z_q [2097152] | loss [1] | indices-as-float [32768]
//
// Numerics contract (DO NOT CHANGE — bitwise-matches the numpy fp32 ref):
//  - code/pixel norms: numpy pairwise-sum tree over 64 rounded squares,
//    fp contract OFF
//  - dot: single c-ordered fma chain per (pixel, code)  (== BLAS sgemm
//    microkernel accumulation)
//  - score: fl(fl(zz+ee) - 2*dot); strict-< first-min, codes visited in
//    ascending-k order at every reduction level (k-step, wave, slice)
//
// Round-6 change: round 5's __launch_bounds__(256,8) capped the allocator
// at 32 VGPRs -> the 8 dot accumulators spilled to scratch (WRITE_SIZE
// 370 MB, VALUBusy 27%). Relaxed to (256,4) — round 4 compiled to 40 VGPRs
// under this bound with zero spills. Structure otherwise identical: z tile
// in LDS as [c/4][px] float4 (imm-offset ds_read_b128, no addr VALU),
// codebook rows wave-uniform -> s_load, SGPR operand folded into v_fmac.

#define DIM       64
#define N_EMB     1024
#define N_PX      32768
#define LOSS_OFF  2097152
#define IDX_OFF   2097153
// loss = 1.25 * sum / 2^21  (exact fp32 constant)
#define LOSS_SCALE 5.9604644775390625e-07f

// numpy pairwise_sum of squares over a 64-float global row, exact tree.
__device__ __forceinline__ float np_sumsq64_row(const float* __restrict__ row) {
    #pragma clang fp contract(off)
    float r[8];
    #pragma unroll
    for (int j = 0; j < 8; ++j) {
        float s = row[j] * row[j];
        #pragma unroll
        for (int m = 1; m < 8; ++m) {
            float p = row[j + 8 * m] * row[j + 8 * m];
            s = s + p;
        }
        r[j] = s;
    }
    return ((r[0] + r[1]) + (r[2] + r[3])) + ((r[4] + r[5]) + (r[6] + r[7]));
}

// Phase 1: grid 2048 = 512 px-groups x 4 code-slices; 256 thr (4 waves).
// Lane owns 1 pixel; wave w owns codes [slice*256 + w*64, +64).
__global__ __launch_bounds__(256, 4)
void vq_argmin(const float* __restrict__ z, const float* __restrict__ cb,
               float* __restrict__ ws_val, int* __restrict__ ws_idx,
               float* __restrict__ out) {
    __shared__ float4 ldsZ[16 * 64];   // [c4][px], 16 KB
    __shared__ float  esq[256];        // this slice's code norms
    __shared__ float  cand_val[4 * 64];
    __shared__ int    cand_idx[4 * 64];

    const int tid  = threadIdx.x;
    const int lane = tid & 63;
    const int wave = __builtin_amdgcn_readfirstlane(tid >> 6);  // uniform
    const int g    = blockIdx.x >> 2;      // px-group 0..511 (64 px each)
    const int s    = blockIdx.x & 3;       // code slice 0..3 (256 codes)
    const int n0   = g * 64;
    const int b    = n0 >> 10;
    const int hw0  = n0 & 1023;
    const size_t zbase = (size_t)b * 65536 + (size_t)hw0;   // z[b][c][hw]

    // ---- stage z tile -> LDS [c4][px] (transposing gather, coalesced) ----
    {
        const int px = tid & 63;
        const int cq = tid >> 6;           // 0..3
        #pragma unroll
        for (int r = 0; r < 4; ++r) {
            const int c4 = cq * 4 + r;
            const float* zp = z + zbase + (size_t)(c4 * 4) * 1024 + px;
            float4 v;
            v.x = zp[0];
            v.y = zp[1024];
            v.z = zp[2048];
            v.w = zp[3072];
            ldsZ[c4 * 64 + px] = v;
        }
    }

    // ---- slice code norms -> LDS (1 row per thread), numpy tree ----
    esq[tid] = np_sumsq64_row(cb + (size_t)(s * 256 + tid) * DIM);

    __syncthreads();

    // ---- zz for this lane's pixel, numpy tree from LDS (bit-identical) ----
    float zz;
    {
        #pragma clang fp contract(off)
        float4 qa = ldsZ[lane];            // c = 0..3
        float4 qb = ldsZ[64 + lane];       // c = 4..7
        float r0 = qa.x * qa.x, r1 = qa.y * qa.y, r2 = qa.z * qa.z, r3 = qa.w * qa.w;
        float r4 = qb.x * qb.x, r5 = qb.y * qb.y, r6 = qb.z * qb.z, r7 = qb.w * qb.w;
        #pragma unroll
        for (int m = 1; m < 8; ++m) {      // r[j] += sq[j + 8m], m ascending
            qa = ldsZ[(2 * m) * 64 + lane];
            qb = ldsZ[(2 * m + 1) * 64 + lane];
            float p;
            p = qa.x * qa.x; r0 = r0 + p;
            p = qa.y * qa.y; r1 = r1 + p;
            p = qa.z * qa.z; r2 = r2 + p;
            p = qa.w * qa.w; r3 = r3 + p;
            p = qb.x * qb.x; r4 = r4 + p;
            p = qb.y * qb.y; r5 = r5 + p;
            p = qb.z * qb.z; r6 = r6 + p;
            p = qb.w * qb.w; r7 = r7 + p;
        }
        zz = ((r0 + r1) + (r2 + r3)) + ((r4 + r5) + (r6 + r7));
    }

    // ---- argmin over this wave's 64-code slice, 8 codes per k-step ----
    float best = FLT_MAX;
    int   bidx = 0;
    const int kb = s * 256 + wave * 64;    // global code base (uniform)
    const int lb = wave * 64;              // local esq base
    for (int kk = 0; kk < 64; kk += 8) {
        const float* e = cb + (size_t)(kb + kk) * DIM;  // uniform -> s_load
        float d0 = 0.f, d1 = 0.f, d2 = 0.f, d3 = 0.f;
        float d4 = 0.f, d5 = 0.f, d6 = 0.f, d7 = 0.f;
        #pragma unroll
        for (int c4 = 0; c4 < 16; ++c4) {
            const float4 vzc = ldsZ[c4 * 64 + lane];   // imm-offset b128
            const int c0 = c4 * 4;
#define VQ_FMA4(DJ, J) \
            DJ = __builtin_fmaf(e[(J)*DIM + c0    ], vzc.x, DJ); \
            DJ = __builtin_fmaf(e[(J)*DIM + c0 + 1], vzc.y, DJ); \
            DJ = __builtin_fmaf(e[(J)*DIM + c0 + 2], vzc.z, DJ); \
            DJ = __builtin_fmaf(e[(J)*DIM + c0 + 3], vzc.w, DJ);
            VQ_FMA4(d0, 0) VQ_FMA4(d1, 1) VQ_FMA4(d2, 2) VQ_FMA4(d3, 3)
            VQ_FMA4(d4, 4) VQ_FMA4(d5, 5) VQ_FMA4(d6, 6) VQ_FMA4(d7, 7)
#undef VQ_FMA4
        }
        // scores, ascending j => first-min kept
#define VQ_SCORE(DJ, J) \
        { \
            float sc; \
            { \
                _Pragma("clang fp contract(off)") \
                const float p = zz + esq[lb + kk + (J)]; \
                sc = p - 2.0f * DJ; \
            } \
            if (sc < best) { best = sc; bidx = kb + kk + (J); } \
        }
        VQ_SCORE(d0, 0) VQ_SCORE(d1, 1) VQ_SCORE(d2, 2) VQ_SCORE(d3, 3)
        VQ_SCORE(d4, 4) VQ_SCORE(d5, 5) VQ_SCORE(d6, 6) VQ_SCORE(d7, 7)
#undef VQ_SCORE
    }
    cand_val[wave * 64 + lane] = best;
    cand_idx[wave * 64 + lane] = bidx;
    __syncthreads();

    // ---- block reduce (4 waves, ascending w == ascending k) -> ws ----
    if (tid < 64) {
        float bv = cand_val[tid];
        int   bi = cand_idx[tid];
        #pragma unroll
        for (int w = 1; w < 4; ++w) {
            float v = cand_val[w * 64 + tid];
            int   i = cand_idx[w * 64 + tid];
            if (v < bv || (v == bv && i < bi)) { bv = v; bi = i; }
        }
        ws_val[s * N_PX + n0 + tid] = bv;
        ws_idx[s * N_PX + n0 + tid] = bi;
    }
    // zero the loss accumulator for phase 2 (stream-ordered before vq_out)
    if (blockIdx.x == 0 && tid == 0) out[LOSS_OFF] = 0.f;
}

// Phase 2: grid 512 x 256 thr; block = 64 px. Reduce 4 slice-candidates
// (ascending slice == ascending k), write indices, z_q, loss.
__global__ __launch_bounds__(256, 4)
void vq_out(const float* __restrict__ z, const float* __restrict__ cb,
            const float* __restrict__ ws_val, const int* __restrict__ ws_idx,
            float* __restrict__ out) {
    __shared__ int   fidx[64];
    __shared__ float lred[4];

    const int tid  = threadIdx.x;
    const int lane = tid & 63;
    const int wave = tid >> 6;
    const int n0   = blockIdx.x * 64;
    const int b    = n0 >> 10;
    const int hw0  = n0 & 1023;
    const size_t zbase = (size_t)b * 65536 + (size_t)hw0;

    if (tid < 64) {
        float bv = ws_val[n0 + tid];
        int   bi = ws_idx[n0 + tid];
        #pragma unroll
        for (int sl = 1; sl < 4; ++sl) {
            float v = ws_val[sl * N_PX + n0 + tid];
            int   i = ws_idx[sl * N_PX + n0 + tid];
            if (v < bv || (v == bv && i < bi)) { bv = v; bi = i; }
        }
        fidx[tid] = bi;
        out[IDX_OFF + n0 + tid] = (float)bi;
    }
    __syncthreads();

    const int px = tid & 63;
    const int cg = tid >> 6;      // 0..3 -> channels cg*16 .. cg*16+15
    const int mi = fidx[px];
    float lacc = 0.f;
    #pragma unroll
    for (int i = 0; i < 16; ++i) {
        const int c = cg * 16 + i;
        float q  = cb[mi * DIM + c];                    // L2-resident gather
        size_t go = zbase + (size_t)c * 1024 + px;
        float zv = z[go];                               // coalesced
        float d  = q - zv;
        lacc = __builtin_fmaf(d, d, lacc);
        out[go] = q;                                    // coalesced
    }
    #pragma unroll
    for (int off = 32; off > 0; off >>= 1)
        lacc += __shfl_down(lacc, off, 64);
    if (lane == 0) lred[wave] = lacc;
    __syncthreads();
    if (tid == 0) {
        float t = (lred[0] + lred[1]) + (lred[2] + lred[3]);
        atomicAdd(&out[LOSS_OFF], t * LOSS_SCALE);
    }
}

extern "C" void kernel_launch(void* const* d_in, const int* in_sizes, int n_in,
                              void* d_out, int out_size, void* d_ws, size_t ws_size,
                              hipStream_t stream) {
    const float* z  = (const float*)d_in[0];   // 2097152 f32
    const float* cb = (const float*)d_in[1];   // 65536 f32
    float* out = (float*)d_out;
    // workspace: 4 x 32768 candidate vals (512 KB) + 4 x 32768 idx (512 KB)
    float* ws_val = (float*)d_ws;
    int*   ws_idx = (int*)((char*)d_ws + 4u * N_PX * sizeof(float));

    vq_argmin<<<2048, 256, 0, stream>>>(z, cb, ws_val, ws_idx, out);
    vq_out<<<512, 256, 0, stream>>>(z, cb, ws_val, ws_idx, out);
}

// Round 7
// 144.465 us; speedup vs baseline: 2.0586x; 1.0538x over previous
//
#include <hip/hip_runtime.h>
#include <float.h>

// VQ-VAE vector quantizer, MI355X fp32 vector-ALU version, round 7.
// z: [32,64,32,32] f32, codebook: [1024,64] f32
// out (f32 flat): z_q [2097152] | loss [1] | indices-as-float [32768]
//
// Numerics contract (DO NOT CHANGE — bitwise-matches the numpy fp32 ref):
//  - code/pixel norms: numpy pairwise-sum tree over 64 rounded squares,
//    fp contract OFF
//  - dot: single c-ordered fma chain per (pixel, code)
//  - score: fl(fl(zz+ee) - 2*dot); strict-< first-min; codes ascending at
//    every reduction level (j within k-step, k-step, wave, slice)
//
// Round-7 change: every prior round bottlenecked on codebook delivery
// (SGPR file too small for 8 rows/k-step -> chunked scalar loads or
// demoted vector loads; r3 with 2x FMA-per-cb-byte was fastest). Now BOTH
// operands live in LDS: z tile [c4][px] (real ds_read_b128), codebook
// slice [code][c4] read with wave-uniform broadcast ds_read_b128 (no
// conflicts, no SGPR pressure, no compiler gamble). 2 px/lane x 8 codes
// per k-step = 1024 FMA : 160 LDS : 80 score.

#define DIM       64
#define N_EMB     1024
#define N_PX      32768
#define LOSS_OFF  2097152
#define IDX_OFF   2097153
// loss = 1.25 * sum / 2^21  (exact fp32 constant)
#define LOSS_SCALE 5.9604644775390625e-07f

// numpy pairwise_sum of squares over a 64-float global row, exact tree.
__device__ __forceinline__ float np_sumsq64_row(const float* __restrict__ row) {
    #pragma clang fp contract(off)
    float r[8];
    #pragma unroll
    for (int j = 0; j < 8; ++j) {
        float s = row[j] * row[j];
        #pragma unroll
        for (int m = 1; m < 8; ++m) {
            float p = row[j + 8 * m] * row[j + 8 * m];
            s = s + p;
        }
        r[j] = s;
    }
    return ((r[0] + r[1]) + (r[2] + r[3])) + ((r[4] + r[5]) + (r[6] + r[7]));
}

// numpy pairwise-sum-of-squares from the LDS z tile ([c4][px], stride 128).
// Bit-identical to np_sumsq64_row on the same 64 values.
__device__ __forceinline__ float np_sumsq64_lds(const float4* ldsZ, int px) {
    #pragma clang fp contract(off)
    float4 qa = ldsZ[px];             // c = 0..3   (j = 0..3)
    float4 qb = ldsZ[128 + px];       // c = 4..7   (j = 4..7)
    float r0 = qa.x * qa.x, r1 = qa.y * qa.y, r2 = qa.z * qa.z, r3 = qa.w * qa.w;
    float r4 = qb.x * qb.x, r5 = qb.y * qb.y, r6 = qb.z * qb.z, r7 = qb.w * qb.w;
    #pragma unroll
    for (int m = 1; m < 8; ++m) {     // r[j] += sq[j + 8m], m ascending
        qa = ldsZ[(2 * m) * 128 + px];
        qb = ldsZ[(2 * m + 1) * 128 + px];
        float p;
        p = qa.x * qa.x; r0 = r0 + p;
        p = qa.y * qa.y; r1 = r1 + p;
        p = qa.z * qa.z; r2 = r2 + p;
        p = qa.w * qa.w; r3 = r3 + p;
        p = qb.x * qb.x; r4 = r4 + p;
        p = qb.y * qb.y; r5 = r5 + p;
        p = qb.z * qb.z; r6 = r6 + p;
        p = qb.w * qb.w; r7 = r7 + p;
    }
    return ((r0 + r1) + (r2 + r3)) + ((r4 + r5) + (r6 + r7));
}

// Phase 1: grid 2048 = 256 px-groups x 8 code-slices; 256 thr (4 waves).
// Block = 128 px (2/lane), slice = 128 codes; wave w owns 32 codes.
__global__ __launch_bounds__(256, 2)
void vq_argmin(const float* __restrict__ z, const float* __restrict__ cb,
               float* __restrict__ ws_val, int* __restrict__ ws_idx,
               float* __restrict__ out) {
    __shared__ float4 ldsZ[16 * 128];   // [c4][px], 32 KB
    __shared__ float4 ldsE[128 * 16];   // [code][c4], 32 KB (bit-exact copy)
    __shared__ float  esq[128];
    __shared__ float  cand_val[4 * 128];
    __shared__ int    cand_idx[4 * 128];

    const int tid  = threadIdx.x;
    const int lane = tid & 63;
    const int wave = __builtin_amdgcn_readfirstlane(tid >> 6);  // uniform
    const int g    = blockIdx.x >> 3;      // px-group 0..255 (128 px each)
    const int s    = blockIdx.x & 7;       // code slice 0..7 (128 codes)
    const int n0   = g * 128;
    const int b    = n0 >> 10;
    const int hw0  = n0 & 1023;
    const size_t zbase = (size_t)b * 65536 + (size_t)hw0;   // z[b][c][hw]

    // ---- stage z tile -> LDS [c4][px] (transposing gather, coalesced) ----
    {
        const int px = tid & 127;
        const int cq = tid >> 7;           // 0..1
        #pragma unroll
        for (int r = 0; r < 8; ++r) {
            const int c4 = cq * 8 + r;
            const float* zp = z + zbase + (size_t)(c4 * 4) * 1024 + px;
            float4 v;
            v.x = zp[0];
            v.y = zp[1024];
            v.z = zp[2048];
            v.w = zp[3072];
            ldsZ[c4 * 128 + px] = v;
        }
    }
    // ---- stage codebook slice -> LDS (bit-exact float4 copy) ----
    {
        const float4* cb4 = (const float4*)(cb + (size_t)s * 128 * DIM);
        #pragma unroll
        for (int r = 0; r < 8; ++r)
            ldsE[r * 256 + tid] = cb4[r * 256 + tid];
    }
    // ---- slice code norms (from global rows; same bits), numpy tree ----
    if (tid < 128)
        esq[tid] = np_sumsq64_row(cb + (size_t)(s * 128 + tid) * DIM);

    __syncthreads();

    // ---- zz for this lane's two pixels (bit-identical tree) ----
    const float zz0 = np_sumsq64_lds(ldsZ, lane);
    const float zz1 = np_sumsq64_lds(ldsZ, lane + 64);

    // ---- argmin over this wave's 32 codes, 8 codes x 2 px per k-step ----
    float best0 = FLT_MAX, best1 = FLT_MAX;
    int   bidx0 = 0,       bidx1 = 0;
    const int kb = s * 128 + wave * 32;    // global code base (uniform)
    const int lw = wave * 32;              // local code base
    for (int kk = 0; kk < 32; kk += 8) {
        float d00 = 0.f, d01 = 0.f, d02 = 0.f, d03 = 0.f;
        float d04 = 0.f, d05 = 0.f, d06 = 0.f, d07 = 0.f;
        float d10 = 0.f, d11 = 0.f, d12 = 0.f, d13 = 0.f;
        float d14 = 0.f, d15 = 0.f, d16 = 0.f, d17 = 0.f;
        #pragma unroll
        for (int c4 = 0; c4 < 16; ++c4) {
            const float4 z0 = ldsZ[c4 * 128 + lane];        // real b128
            const float4 z1 = ldsZ[c4 * 128 + 64 + lane];   // real b128
#define VQ_CODE(J) \
            { \
                const float4 e4 = ldsE[(lw + kk + (J)) * 16 + c4]; /* broadcast */ \
                d0##J = __builtin_fmaf(e4.x, z0.x, d0##J); \
                d0##J = __builtin_fmaf(e4.y, z0.y, d0##J); \
                d0##J = __builtin_fmaf(e4.z, z0.z, d0##J); \
                d0##J = __builtin_fmaf(e4.w, z0.w, d0##J); \
                d1##J = __builtin_fmaf(e4.x, z1.x, d1##J); \
                d1##J = __builtin_fmaf(e4.y, z1.y, d1##J); \
                d1##J = __builtin_fmaf(e4.z, z1.z, d1##J); \
                d1##J = __builtin_fmaf(e4.w, z1.w, d1##J); \
            }
            VQ_CODE(0) VQ_CODE(1) VQ_CODE(2) VQ_CODE(3)
            VQ_CODE(4) VQ_CODE(5) VQ_CODE(6) VQ_CODE(7)
#undef VQ_CODE
        }
        // scores, ascending J => first-min kept
#define VQ_SCORE(J) \
        { \
            const float ee = esq[lw + kk + (J)]; \
            float sc0, sc1; \
            { \
                _Pragma("clang fp contract(off)") \
                const float p0 = zz0 + ee; \
                const float p1 = zz1 + ee; \
                sc0 = p0 - 2.0f * d0##J; \
                sc1 = p1 - 2.0f * d1##J; \
            } \
            if (sc0 < best0) { best0 = sc0; bidx0 = kb + kk + (J); } \
            if (sc1 < best1) { best1 = sc1; bidx1 = kb + kk + (J); } \
        }
        VQ_SCORE(0) VQ_SCORE(1) VQ_SCORE(2) VQ_SCORE(3)
        VQ_SCORE(4) VQ_SCORE(5) VQ_SCORE(6) VQ_SCORE(7)
#undef VQ_SCORE
    }
    cand_val[wave * 128 + lane]      = best0;
    cand_idx[wave * 128 + lane]      = bidx0;
    cand_val[wave * 128 + 64 + lane] = best1;
    cand_idx[wave * 128 + 64 + lane] = bidx1;
    __syncthreads();

    // ---- block reduce (4 waves, ascending w == ascending k) -> ws ----
    if (tid < 128) {
        float bv = cand_val[tid];
        int   bi = cand_idx[tid];
        #pragma unroll
        for (int w = 1; w < 4; ++w) {
            float v = cand_val[w * 128 + tid];
            int   i = cand_idx[w * 128 + tid];
            if (v < bv || (v == bv && i < bi)) { bv = v; bi = i; }
        }
        ws_val[s * N_PX + n0 + tid] = bv;
        ws_idx[s * N_PX + n0 + tid] = bi;
    }
    // zero the loss accumulator for phase 2 (stream-ordered before vq_out)
    if (blockIdx.x == 0 && tid == 0) out[LOSS_OFF] = 0.f;
}

// Phase 2: grid 512 x 256 thr; block = 64 px. Reduce 8 slice-candidates
// (ascending slice == ascending k), write indices, z_q, loss.
__global__ __launch_bounds__(256, 4)
void vq_out(const float* __restrict__ z, const float* __restrict__ cb,
            const float* __restrict__ ws_val, const int* __restrict__ ws_idx,
            float* __restrict__ out) {
    __shared__ int   fidx[64];
    __shared__ float lred[4];

    const int tid  = threadIdx.x;
    const int lane = tid & 63;
    const int wave = tid >> 6;
    const int n0   = blockIdx.x * 64;
    const int b    = n0 >> 10;
    const int hw0  = n0 & 1023;
    const size_t zbase = (size_t)b * 65536 + (size_t)hw0;

    if (tid < 64) {
        float bv = ws_val[n0 + tid];
        int   bi = ws_idx[n0 + tid];
        #pragma unroll
        for (int sl = 1; sl < 8; ++sl) {
            float v = ws_val[sl * N_PX + n0 + tid];
            int   i = ws_idx[sl * N_PX + n0 + tid];
            if (v < bv || (v == bv && i < bi)) { bv = v; bi = i; }
        }
        fidx[tid] = bi;
        out[IDX_OFF + n0 + tid] = (float)bi;
    }
    __syncthreads();

    const int px = tid & 63;
    const int cg = tid >> 6;      // 0..3 -> channels cg*16 .. cg*16+15
    const int mi = fidx[px];
    float lacc = 0.f;
    #pragma unroll
    for (int i = 0; i < 16; ++i) {
        const int c = cg * 16 + i;
        float q  = cb[mi * DIM + c];                    // L2-resident gather
        size_t go = zbase + (size_t)c * 1024 + px;
        float zv = z[go];                               // coalesced
        float d  = q - zv;
        lacc = __builtin_fmaf(d, d, lacc);
        out[go] = q;                                    // coalesced
    }
    #pragma unroll
    for (int off = 32; off > 0; off >>= 1)
        lacc += __shfl_down(lacc, off, 64);
    if (lane == 0) lred[wave] = lacc;
    __syncthreads();
    if (tid == 0) {
        float t = (lred[0] + lred[1]) + (lred[2] + lred[3]);
        atomicAdd(&out[LOSS_OFF], t * LOSS_SCALE);
    }
}

extern "C" void kernel_launch(void* const* d_in, const int* in_sizes, int n_in,
                              void* d_out, int out_size, void* d_ws, size_t ws_size,
                              hipStream_t stream) {
    const float* z  = (const float*)d_in[0];   // 2097152 f32
    const float* cb = (const float*)d_in[1];   // 65536 f32
    float* out = (float*)d_out;
    // workspace: 8 x 32768 vals (1 MB) + 8 x 32768 idx (1 MB)
    float* ws_val = (float*)d_ws;
    int*   ws_idx = (int*)((char*)d_ws + 8u * N_PX * sizeof(float));

    vq_argmin<<<2048, 256, 0, stream>>>(z, cb, ws_val, ws_idx, out);
    vq_out<<<512, 256, 0, stream>>>(z, cb, ws_val, ws_idx, out);
}